// Round 11
// baseline (641.974 us; speedup 1.0000x reference)
//
#include <hip/hip_runtime.h>
#include <hip/hip_bf16.h>
#include <stdint.h>

// ArcFace fused: out[n][c] = 64 * margin(clip( (x_hat . w_c) / ||w_c|| ))
// N=512, D=512, C=100000.
// R10 (resubmit after broker timeout): barrier-free streaming GEMM. No LDS,
// no __syncthreads in the GEMM.
//  - per wave: 64x32 output tile, acc[4][2] of 16x16x32 bf16 MFMA (32 VGPR)
//  - A (pre-normalized bf16, 0.5 MB, L2-hot): fragments loaded per K-step
//    straight from global (16 rows x 64B per instr)
//  - B (raw f32 W, L3-hot from harness restore): per-lane loads 1 iter ahead,
//    in-register v_cvt_pk_bf16_f32, sum(w^2) accumulated on the f32s and
//    reduced with 2 shfl_xor (kg quarters) -> rsqrt in epilogue
//  - label margin fused into the epilogue (no fixup kernel)
// Rationale (R2 vs R6 measured): GEMM time tracks waves/CU, not barrier
// discipline. This structure has zero sync and ~90-100 VGPR -> max TLP.

#define NROWS 512
#define DDIM  512
#define NCLS  100000
#define NCOLP 1563          // ceil(100000/64) panels of 64 classes
#define FULLP 1560          // panels covered by the 8-panel XCD groups

typedef __attribute__((ext_vector_type(8))) short bf16x8;
typedef __attribute__((ext_vector_type(4))) float f32x4;

__device__ __forceinline__ unsigned short f2bf(float x) {
    union { float f; uint32_t u; } c; c.f = x;
    uint32_t r = (c.u + 0x7FFFu + ((c.u >> 16) & 1u)) >> 16;
    return (unsigned short)r;
}

// pack 2 f32 -> 1 u32 of 2 bf16 (RNE), low = a, high = b
__device__ __forceinline__ uint32_t cvtpk(float a, float b) {
    uint32_t r;
    asm("v_cvt_pk_bf16_f32 %0, %1, %2" : "=v"(r) : "v"(a), "v"(b));
    return r;
}

// Normalize x rows to unit L2 norm, store bf16. 512 rows, one wave each.
__global__ __launch_bounds__(256)
void rownorm_x(const float* __restrict__ in, unsigned short* __restrict__ out) {
    const int row  = blockIdx.x * 4 + (threadIdx.x >> 6);
    const int lane = threadIdx.x & 63;

    const float4* p = (const float4*)(in + (size_t)row * DDIM);
    float4 v0 = p[lane];
    float4 v1 = p[64 + lane];

    float ss = v0.x*v0.x + v0.y*v0.y + v0.z*v0.z + v0.w*v0.w
             + v1.x*v1.x + v1.y*v1.y + v1.z*v1.z + v1.w*v1.w;
    #pragma unroll
    for (int off = 32; off > 0; off >>= 1) ss += __shfl_xor(ss, off);
    const float r = rsqrtf(ss);

    unsigned short* orow = out + (size_t)row * DDIM;
    ushort4 o0, o1;
    o0.x = f2bf(v0.x * r); o0.y = f2bf(v0.y * r);
    o0.z = f2bf(v0.z * r); o0.w = f2bf(v0.w * r);
    o1.x = f2bf(v1.x * r); o1.y = f2bf(v1.y * r);
    o1.z = f2bf(v1.z * r); o1.w = f2bf(v1.w * r);
    *(ushort4*)(orow + lane * 4) = o0;
    *(ushort4*)(orow + 256 + lane * 4) = o1;
}

// Streaming GEMM: block = 4 waves (2x2), block tile 128 rows x 64 classes.
// Grid: 1563 panels x 4 row-slots = 6252 blocks, XCD-grouped so the 4 slots
// of a panel share bid%8 (same XCD L2 -> W panel fetched once).
__global__ __launch_bounds__(256)
void arcface_stream(const unsigned short* __restrict__ A,
                    const float* __restrict__ W,
                    const int* __restrict__ labels,
                    float* __restrict__ out) {
    const int bid = blockIdx.x;
    int panel, slot;
    if (bid < FULLP * 4) { panel = (bid >> 5) * 8 + (bid & 7); slot = (bid >> 3) & 3; }
    else                 { int l = bid - FULLP * 4; panel = FULLP + l % 3; slot = l / 3; }
    const int rowBase = slot * 128;
    const int colBase = panel * 64;

    const int t    = threadIdx.x;
    const int lane = t & 63;
    const int wid  = t >> 6;
    const int wr   = wid >> 1;          // wave row 0..1 (64 rows each)
    const int wc   = wid & 1;           // wave col 0..1 (32 classes each)
    const int fr   = lane & 15;
    const int kg   = (lane >> 4) << 3;  // k-offset within 32-chunk: 0,8,16,24

    // A fragment base pointers: row = rowBase + wr*64 + m*16 + fr
    const unsigned short* aBase[4];
    #pragma unroll
    for (int m = 0; m < 4; ++m)
        aBase[m] = A + (size_t)(rowBase + wr * 64 + m * 16 + fr) * DDIM + kg;

    // B fragment base pointers: class = colBase + wc*32 + n*16 + fr (clamped)
    const float* bBase[2];
    int bcls[2];
    #pragma unroll
    for (int n = 0; n < 2; ++n) {
        bcls[n] = colBase + wc * 32 + n * 16 + fr;
        const int cr = bcls[n] < NCLS ? bcls[n] : NCLS - 1;   // clamp, never OOB
        bBase[n] = W + (size_t)cr * DDIM + kg;
    }

    f32x4 acc[4][2] = {};
    float ssq[2] = {0.f, 0.f};

    // prologue: B chunk for kt=0 in flight
    float4 fB[2][2];
    #pragma unroll
    for (int n = 0; n < 2; ++n) {
        fB[n][0] = *(const float4*)(bBase[n] + 0);
        fB[n][1] = *(const float4*)(bBase[n] + 4);
    }

    #pragma unroll
    for (int tt = 0; tt < 16; ++tt) {
        const int kt = tt * 32;

        // issue A loads for this step (L2-hot, covered by cvt phase + TLP)
        bf16x8 a[4];
        #pragma unroll
        for (int m = 0; m < 4; ++m)
            a[m] = *(const bf16x8*)(aBase[m] + kt);

        // convert prev-issued B f32 -> bf16 frags, accumulate sum(w^2)
        bf16x8 b[2];
        #pragma unroll
        for (int n = 0; n < 2; ++n) {
            const float4 lo = fB[n][0], hi = fB[n][1];
            ssq[n] += lo.x*lo.x + lo.y*lo.y + lo.z*lo.z + lo.w*lo.w
                    + hi.x*hi.x + hi.y*hi.y + hi.z*hi.z + hi.w*hi.w;
            uint32_t u0 = cvtpk(lo.x, lo.y);
            uint32_t u1 = cvtpk(lo.z, lo.w);
            uint32_t u2 = cvtpk(hi.x, hi.y);
            uint32_t u3 = cvtpk(hi.z, hi.w);
            union { uint32_t u[4]; bf16x8 v; } pk;
            pk.u[0] = u0; pk.u[1] = u1; pk.u[2] = u2; pk.u[3] = u3;
            b[n] = pk.v;
        }

        // issue B loads for next step (cover = MFMA + next iter's A issue + TLP)
        if (tt < 15) {
            #pragma unroll
            for (int n = 0; n < 2; ++n) {
                fB[n][0] = *(const float4*)(bBase[n] + kt + 32);
                fB[n][1] = *(const float4*)(bBase[n] + kt + 36);
            }
        }

        #pragma unroll
        for (int m = 0; m < 4; ++m)
            #pragma unroll
            for (int n = 0; n < 2; ++n)
                acc[m][n] = __builtin_amdgcn_mfma_f32_16x16x32_bf16(
                    a[m], b[n], acc[m][n], 0, 0, 0);
    }

    // reduce sum(w^2) across the 4 kg-quarters (lanes fr, fr+16, fr+32, fr+48)
    float rn[2];
    #pragma unroll
    for (int n = 0; n < 2; ++n) {
        float s = ssq[n];
        s += __shfl_xor(s, 16);
        s += __shfl_xor(s, 32);
        rn[n] = rsqrtf(s);
    }

    // epilogue: normalize, clip, label margin, scale, store.
    // C/D layout: col = lane&15 (=fr), row = (lane>>4)*4 + i
    const float lo = -1.0f + 1e-7f, hi = 1.0f - 1e-7f;
    const float COSM = 0.8775825618903728f;    // cos(0.5)
    const float SINM = 0.479425538604203f;     // sin(0.5)
    const float MM   = 0.2397127693021015f;    // sin(0.5)*0.5
    const float THR  = -0.8775825618903728f;   // cos(pi-0.5)

    #pragma unroll
    for (int m = 0; m < 4; ++m) {
        #pragma unroll
        for (int i = 0; i < 4; ++i) {
            const int r = rowBase + wr * 64 + m * 16 + ((lane >> 4) << 2) + i;
            const int lab = labels[r];
            #pragma unroll
            for (int n = 0; n < 2; ++n) {
                const int c = bcls[n];
                if (c < NCLS) {
                    const float raw = acc[m][n][i] * rn[n];
                    const float tc  = fminf(fmaxf(raw, lo), hi);
                    float val = tc;
                    if (lab == c) {
                        val = (raw > THR)
                            ? tc * COSM - sqrtf(fmaxf(1.0f - tc * tc, 0.0f)) * SINM
                            : tc - MM;
                    }
                    out[(size_t)r * NCLS + c] = 64.0f * val;
                }
            }
        }
    }
}

extern "C" void kernel_launch(void* const* d_in, const int* in_sizes, int n_in,
                              void* d_out, int out_size, void* d_ws, size_t ws_size,
                              hipStream_t stream) {
    const float* x     = (const float*)d_in[0];
    const int*   label = (const int*)d_in[1];
    const float* w     = (const float*)d_in[2];
    float* out = (float*)d_out;

    unsigned short* Abf = (unsigned short*)d_ws;   // 512*512 bf16

    rownorm_x<<<NROWS / 4, 256, 0, stream>>>(x, Abf);

    arcface_stream<<<NCOLP * 4, 256, 0, stream>>>(Abf, w, label, out);
}